// Round 7
// baseline (180.365 us; speedup 1.0000x reference)
//
#include <hip/hip_runtime.h>

// Problem constants (fixed by the reference file)
#define BATCH   8
#define NVERT   50000
#define CIN     32
#define LSP     9
#define COUT    64
#define MVERT   12500
#define NNZ     37500

#define TILE_T  256            // tasks per block (64 per wave)
#define TPB     147            // ceil(NNZ/256)
#define NFRAG   2304           // 9 s * 4 g * 64 lanes (B fragments)
#define OUTDW   (BATCH * MVERT * COUT)

#define PRE_BLOCKS  6250
#define PACK_BLOCKS 9
#define ZERO_BLOCKS 6250
#define HZ_BLOCKS   49

typedef __attribute__((ext_vector_type(8))) short  short8;
typedef __attribute__((ext_vector_type(4))) float  floatx4;

static __device__ __forceinline__ unsigned short f2bf(float f) {
    union { float f; unsigned int u; } c; c.f = f;
    unsigned int u = c.u;
    return (unsigned short)((u + 0x7fffu + ((u >> 16) & 1u)) >> 16);
}

// async 16B global->LDS DMA; lds dest = wave-uniform base + lane*16
static __device__ __forceinline__ void dma16(const void* g, void* l) {
    typedef __attribute__((address_space(1))) const void gvoid;
    typedef __attribute__((address_space(3))) void lvoid;
    __builtin_amdgcn_global_load_lds(
        (gvoid*)(unsigned long long)g,
        (lvoid*)(unsigned int)(unsigned long long)l,
        16, 0, 0);
}

// ---- k1: precast x | pack W | zero out | zero hist
__global__ __launch_bounds__(256)
void prep_kernel(const float* __restrict__ x, const float* __restrict__ w,
                 unsigned short* __restrict__ x16, unsigned short* __restrict__ wp,
                 float* __restrict__ out, int* __restrict__ hist)
{
    const int blk = blockIdx.x;
    const int tid = threadIdx.x;
    if (blk < PRE_BLOCKS) {
        const size_t base = ((size_t)blk * 256 + tid) * 8;
        const float4* s = (const float4*)(x + base);
        float4 a = s[0], c = s[1];
        unsigned short t[8];
        t[0]=f2bf(a.x); t[1]=f2bf(a.y); t[2]=f2bf(a.z); t[3]=f2bf(a.w);
        t[4]=f2bf(c.x); t[5]=f2bf(c.y); t[6]=f2bf(c.z); t[7]=f2bf(c.w);
        *(uint4*)(x16 + base) = *(uint4*)t;
    } else if (blk < PRE_BLOCKS + PACK_BLOCKS) {
        // B-frag f=(s*4+g)*64+lane holds W[s*32+(lane>>4)*8+j][g*16+(lane&15)]
        const int f = (blk - PRE_BLOCKS) * 256 + tid;
        if (f < NFRAG) {
            int s = f >> 8, g = (f >> 6) & 3, lane = f & 63;
            int k0 = s * 32 + (lane >> 4) * 8, col = g * 16 + (lane & 15);
            unsigned short t[8];
            #pragma unroll
            for (int j = 0; j < 8; ++j)
                t[j] = f2bf(w[(size_t)(k0 + j) * COUT + col]);
            ((uint4*)wp)[f] = *(uint4*)t;
        }
    } else if (blk < PRE_BLOCKS + PACK_BLOCKS + ZERO_BLOCKS) {
        const size_t base = ((size_t)(blk - PRE_BLOCKS - PACK_BLOCKS) * 256 + tid) * 4;
        if (base < OUTDW) *(uint4*)(out + base) = (uint4){0, 0, 0, 0};
    } else {
        const int i = (blk - PRE_BLOCKS - PACK_BLOCKS - ZERO_BLOCKS) * 256 + tid;
        if (i < MVERT) hist[i] = 0;
    }
}

// ---- k2: histogram of rows
__global__ __launch_bounds__(256)
void hist_kernel(const int* __restrict__ rows, int* __restrict__ hist) {
    int z = blockIdx.x * 256 + threadIdx.x;
    if (z < NNZ) atomicAdd(&hist[rows[z]], 1);
}

// ---- k3: exclusive scan of hist -> off2 (single block)
__global__ __launch_bounds__(1024)
void scan_kernel(const int* __restrict__ hist, int* __restrict__ off2) {
    __shared__ int sh[1024];
    const int t = threadIdx.x;
    const int base = t * 13;
    int loc[13];
    int s = 0;
    #pragma unroll
    for (int j = 0; j < 13; ++j) {
        int i = base + j;
        int v = (i < MVERT) ? hist[i] : 0;
        loc[j] = s; s += v;
    }
    sh[t] = s;
    __syncthreads();
    for (int d = 1; d < 1024; d <<= 1) {
        int v = (t >= d) ? sh[t - d] : 0;
        __syncthreads();
        sh[t] += v;
        __syncthreads();
    }
    const int excl = sh[t] - s;
    #pragma unroll
    for (int j = 0; j < 13; ++j) {
        int i = base + j;
        if (i < MVERT) off2[i] = excl + loc[j];
    }
}

// ---- k4: scatter into row-sorted order
__global__ __launch_bounds__(256)
void scatter_kernel(const int* __restrict__ rows, const int* __restrict__ cols,
                    const float* __restrict__ vals, int* __restrict__ off2,
                    int* __restrict__ rows_s, int* __restrict__ cols_s,
                    float* __restrict__ vals_s) {
    int z = blockIdx.x * 256 + threadIdx.x;
    if (z < NNZ) {
        int r = rows[z];
        int pos = atomicAdd(&off2[r], 1);
        rows_s[pos] = r;
        cols_s[pos] = cols[z];
        vals_s[pos] = vals[z];
    }
}

// ---- k4b: packed per-task spiral indices (uint16), 32B/task, batch-shared.
// One divergent pass here replaces 8x divergent re-walks in the hot kernel.
__global__ __launch_bounds__(256)
void tidx_kernel(const int* __restrict__ cols_s, const int* __restrict__ spiral,
                 unsigned short* __restrict__ tidx) {
    int z = blockIdx.x * 256 + threadIdx.x;
    if (z < NNZ) {
        const int c = cols_s[z];
        unsigned short t[16];
        #pragma unroll
        for (int s = 0; s < 9; ++s) t[s] = (unsigned short)spiral[c * LSP + s];
        #pragma unroll
        for (int s = 9; s < 16; ++s) t[s] = 0;
        uint4* dst = (uint4*)(tidx + (size_t)z * 16);
        dst[0] = *(uint4*)t;
        dst[1] = *(uint4*)(t + 8);
    }
}

// ---- k5: fused gather+GEMM+ELU+scale + run-aggregated scatter-add
// 64 tasks/wave (4 M-tiles share B). B-frags in LDS (ds_read_b128, 0 TA reqs).
// Indices from packed tidx (2 coalesced loads/lane). A-frags global->VGPR,
// software-pipelined one k-step ahead. Single barrier (W staging).
__global__ __launch_bounds__(256, 3)
void spiral_mfma5_kernel(const unsigned short* __restrict__ x16,
                         const unsigned short* __restrict__ wp,
                         const float* __restrict__ bias,
                         const unsigned short* __restrict__ tidx,
                         const int* __restrict__ rows_s,
                         const float* __restrict__ vals_s,
                         float* __restrict__ out)
{
    __shared__ uint4 sWP4[NFRAG];       // 36,864 B: W fragments
    __shared__ float sS[4 * 16 * 68];   // 17,408 B: epilogue transpose

    const int bid  = blockIdx.x;
    const int b    = bid & 7;          // XCD swizzle: batch <-> XCD
    const int tile = bid >> 3;
    const int tid  = threadIdx.x;
    const int w    = tid >> 6;
    const int lane = tid & 63;
    const int quad = lane >> 4;
    const int m16  = lane & 15;
    const int z0w  = tile * TILE_T + 64 * w;

    // ---- stage W into LDS: 2304 frags, 9 x 16B per thread (wave-uniform+lane*16)
    #pragma unroll
    for (int i = 0; i < 9; ++i)
        dma16(wp + (size_t)(i * 256 + tid) * 8, (char*)sWP4 + (i * 256 + tid) * 16);

    // ---- per-lane task metadata (all coalesced)
    const int   zc   = min(z0w + lane, NNZ - 1);
    const int   rowv = rows_s[zc];
    const float valv = vals_s[zc];
    const uint4 p0 = *(const uint4*)(tidx + (size_t)zc * 16);
    const uint  p1 = *(const unsigned int*)(tidx + (size_t)zc * 16 + 8);
    int idx[9];
    idx[0] = p0.x & 0xffff;  idx[1] = p0.x >> 16;
    idx[2] = p0.y & 0xffff;  idx[3] = p0.y >> 16;
    idx[4] = p0.z & 0xffff;  idx[5] = p0.z >> 16;
    idx[6] = p0.w & 0xffff;  idx[7] = p0.w >> 16;
    idx[8] = p1 & 0xffff;

    const unsigned short* xb = x16 + (size_t)b * NVERT * CIN;

    floatx4 acc[4][4];
    #pragma unroll
    for (int mt = 0; mt < 4; ++mt)
        #pragma unroll
        for (int g = 0; g < 4; ++g) acc[mt][g] = (floatx4){0.f, 0.f, 0.f, 0.f};

    __syncthreads();   // W staged (drains vmcnt incl. lds-DMA)

    const unsigned short* sWP = (const unsigned short*)sWP4;

    // ---- K-loop, one k-step ahead on the A-gathers
    short8 a_cur[4], a_nxt[4];
    #pragma unroll
    for (int mt = 0; mt < 4; ++mt) {
        int tix = __shfl(idx[0], mt * 16 + m16);
        a_cur[mt] = *(const short8*)(xb + (size_t)tix * CIN + quad * 8);
    }
    #pragma unroll
    for (int s = 0; s < 9; ++s) {
        if (s < 8) {
            #pragma unroll
            for (int mt = 0; mt < 4; ++mt) {
                int tix = __shfl(idx[s + 1], mt * 16 + m16);
                a_nxt[mt] = *(const short8*)(xb + (size_t)tix * CIN + quad * 8);
            }
        }
        short8 bf[4];
        #pragma unroll
        for (int g = 0; g < 4; ++g)
            bf[g] = *(const short8*)(sWP + (size_t)((s * 4 + g) * 64 + lane) * 8);
        #pragma unroll
        for (int mt = 0; mt < 4; ++mt)
            #pragma unroll
            for (int g = 0; g < 4; ++g)
                acc[mt][g] = __builtin_amdgcn_mfma_f32_16x16x32_bf16(a_cur[mt], bf[g], acc[mt][g], 0, 0, 0);
        if (s < 8) {
            #pragma unroll
            for (int mt = 0; mt < 4; ++mt) a_cur[mt] = a_nxt[mt];
        }
    }

    // ---- epilogue per M-tile: bias+ELU+scale -> LDS transpose -> sorted-run atomics
    float* region = sS + w * (16 * 68);
    float bs[4];
    #pragma unroll
    for (int g = 0; g < 4; ++g) bs[g] = bias[g * 16 + m16];

    float* outb = out + (size_t)b * MVERT * COUT;

    #pragma unroll
    for (int mt = 0; mt < 4; ++mt) {
        const int zbase = z0w + mt * 16;
        int nval = NNZ - zbase;
        nval = (nval < 0) ? 0 : ((nval > 16) ? 16 : nval);
        if (nval <= 0) continue;   // wave-uniform

        // C layout: ch col = g*16+m16, task row = quad*4+reg
        #pragma unroll
        for (int r = 0; r < 4; ++r) {
            const int tt = quad * 4 + r;
            const float vv = __shfl(valv, mt * 16 + tt);
            #pragma unroll
            for (int g = 0; g < 4; ++g) {
                float y = acc[mt][g][r] + bs[g];
                y = (y > 0.0f) ? y : (__expf(y) - 1.0f);
                region[tt * 68 + g * 16 + m16] = y * vv;
            }
        }

        // run aggregation over sorted rows: lane = channel
        float a = 0.0f;
        int cur = __shfl(rowv, mt * 16);
        for (int t = 0; t < nval; ++t) {
            int rt = __shfl(rowv, mt * 16 + t);
            if (rt != cur) {
                atomicAdd(outb + (size_t)cur * COUT + lane, a);
                a = 0.0f; cur = rt;
            }
            a += region[t * 68 + lane];
        }
        atomicAdd(outb + (size_t)cur * COUT + lane, a);
    }
}

extern "C" void kernel_launch(void* const* d_in, const int* in_sizes, int n_in,
                              void* d_out, int out_size, void* d_ws, size_t ws_size,
                              hipStream_t stream) {
    const float* x      = (const float*)d_in[0];
    const float* w      = (const float*)d_in[1];
    const float* bias   = (const float*)d_in[2];
    const float* vals   = (const float*)d_in[3];
    const int*   spiral = (const int*)d_in[4];
    const int*   rows   = (const int*)d_in[5];
    const int*   cols   = (const int*)d_in[6];
    float* out = (float*)d_out;

    // ws layout
    char* base = (char*)d_ws;
    unsigned short* wp     = (unsigned short*)(base);                    //    36,864 B
    unsigned short* x16    = (unsigned short*)(base + 36864);            // 25,600,000 B
    int*            hist   = (int*)(base + 25636864);
    int*            off2   = (int*)(base + 25686864);
    int*            rows_s = (int*)(base + 25736864);
    int*            cols_s = (int*)(base + 25886880);
    float*          vals_s = (float*)(base + 26036896);
    unsigned short* tidx   = (unsigned short*)(base + 26186912);         //  1,200,000 B

    const int prep_grid = PRE_BLOCKS + PACK_BLOCKS + ZERO_BLOCKS + HZ_BLOCKS;
    prep_kernel<<<prep_grid, 256, 0, stream>>>(x, w, x16, wp, out, hist);
    hist_kernel<<<147, 256, 0, stream>>>(rows, hist);
    scan_kernel<<<1, 1024, 0, stream>>>(hist, off2);
    scatter_kernel<<<147, 256, 0, stream>>>(rows, cols, vals, off2,
                                            rows_s, cols_s, vals_s);
    tidx_kernel<<<147, 256, 0, stream>>>(cols_s, spiral, tidx);
    spiral_mfma5_kernel<<<BATCH * TPB, 256, 0, stream>>>(x16, wp, bias, tidx,
                                                         rows_s, vals_s, out);
}

// Round 8
// 177.212 us; speedup vs baseline: 1.0178x; 1.0178x over previous
//
#include <hip/hip_runtime.h>

// Problem constants (fixed by the reference file)
#define BATCH   8
#define NVERT   50000
#define CIN     32
#define LSP     9
#define COUT    64
#define MVERT   12500
#define NNZ     37500

#define NFRAG   2304           // 9 s * 4 g * 64 lanes (B fragments)
#define OUTDW   (BATCH * MVERT * COUT)

#define TILE_T  128            // tasks per block (32 per wave, 2 M-tiles)
#define TPB     293            // ceil(37500/128)

#define PRE_BLOCKS  6250
#define PACK_BLOCKS 9
#define ZERO_BLOCKS 6250
#define HZ_BLOCKS   49

typedef __attribute__((ext_vector_type(8))) short  short8;
typedef __attribute__((ext_vector_type(4))) float  floatx4;

static __device__ __forceinline__ unsigned short f2bf(float f) {
    union { float f; unsigned int u; } c; c.f = f;
    unsigned int u = c.u;
    return (unsigned short)((u + 0x7fffu + ((u >> 16) & 1u)) >> 16);
}

// ---- k1: precast x | pack W | zero out | zero hist
__global__ __launch_bounds__(256)
void prep_kernel(const float* __restrict__ x, const float* __restrict__ w,
                 unsigned short* __restrict__ x16, unsigned short* __restrict__ wp,
                 float* __restrict__ out, int* __restrict__ hist)
{
    const int blk = blockIdx.x;
    const int tid = threadIdx.x;
    if (blk < PRE_BLOCKS) {
        const size_t base = ((size_t)blk * 256 + tid) * 8;
        const float4* s = (const float4*)(x + base);
        float4 a = s[0], c = s[1];
        unsigned short t[8];
        t[0]=f2bf(a.x); t[1]=f2bf(a.y); t[2]=f2bf(a.z); t[3]=f2bf(a.w);
        t[4]=f2bf(c.x); t[5]=f2bf(c.y); t[6]=f2bf(c.z); t[7]=f2bf(c.w);
        *(uint4*)(x16 + base) = *(uint4*)t;
    } else if (blk < PRE_BLOCKS + PACK_BLOCKS) {
        // B-frag f=(s*4+g)*64+lane holds W[s*32+(lane>>4)*8+j][g*16+(lane&15)]
        const int f = (blk - PRE_BLOCKS) * 256 + tid;
        if (f < NFRAG) {
            int s = f >> 8, g = (f >> 6) & 3, lane = f & 63;
            int k0 = s * 32 + (lane >> 4) * 8, col = g * 16 + (lane & 15);
            unsigned short t[8];
            #pragma unroll
            for (int j = 0; j < 8; ++j)
                t[j] = f2bf(w[(size_t)(k0 + j) * COUT + col]);
            ((uint4*)wp)[f] = *(uint4*)t;
        }
    } else if (blk < PRE_BLOCKS + PACK_BLOCKS + ZERO_BLOCKS) {
        const size_t base = ((size_t)(blk - PRE_BLOCKS - PACK_BLOCKS) * 256 + tid) * 4;
        if (base < OUTDW) *(uint4*)(out + base) = (uint4){0, 0, 0, 0};
    } else {
        const int i = (blk - PRE_BLOCKS - PACK_BLOCKS - ZERO_BLOCKS) * 256 + tid;
        if (i < MVERT) hist[i] = 0;
    }
}

// ---- k2: histogram of rows
__global__ __launch_bounds__(256)
void hist_kernel(const int* __restrict__ rows, int* __restrict__ hist) {
    int z = blockIdx.x * 256 + threadIdx.x;
    if (z < NNZ) atomicAdd(&hist[rows[z]], 1);
}

// ---- k3: exclusive scan of hist -> off2 (single block)
__global__ __launch_bounds__(1024)
void scan_kernel(const int* __restrict__ hist, int* __restrict__ off2) {
    __shared__ int sh[1024];
    const int t = threadIdx.x;
    const int base = t * 13;
    int loc[13];
    int s = 0;
    #pragma unroll
    for (int j = 0; j < 13; ++j) {
        int i = base + j;
        int v = (i < MVERT) ? hist[i] : 0;
        loc[j] = s; s += v;
    }
    sh[t] = s;
    __syncthreads();
    for (int d = 1; d < 1024; d <<= 1) {
        int v = (t >= d) ? sh[t - d] : 0;
        __syncthreads();
        sh[t] += v;
        __syncthreads();
    }
    const int excl = sh[t] - s;
    #pragma unroll
    for (int j = 0; j < 13; ++j) {
        int i = base + j;
        if (i < MVERT) off2[i] = excl + loc[j];
    }
}

// ---- k4: scatter into row-sorted order + build packed per-task spiral indices
__global__ __launch_bounds__(256)
void scatter_kernel(const int* __restrict__ rows, const int* __restrict__ cols,
                    const float* __restrict__ vals, const int* __restrict__ spiral,
                    int* __restrict__ off2,
                    int* __restrict__ rows_s, float* __restrict__ vals_s,
                    unsigned short* __restrict__ tidx) {
    int z = blockIdx.x * 256 + threadIdx.x;
    if (z < NNZ) {
        int r = rows[z];
        int c = cols[z];
        int pos = atomicAdd(&off2[r], 1);
        rows_s[pos] = r;
        vals_s[pos] = vals[z];
        unsigned short t[16];
        #pragma unroll
        for (int s = 0; s < 9; ++s) t[s] = (unsigned short)spiral[c * LSP + s];
        #pragma unroll
        for (int s = 9; s < 16; ++s) t[s] = 0;
        uint4* dst = (uint4*)(tidx + (size_t)pos * 16);
        dst[0] = *(uint4*)t;
        dst[1] = *(uint4*)(t + 8);
    }
}

// ---- k5: fused gather+GEMM+ELU+scale + register-aggregated scatter-add
// 32 tasks/wave (2 M-tiles). ALL 18 A-fragment gathers issued up front
// (one latency round-trip). B-frags from global (L1/L2-resident 36 KB).
// Zero LDS, zero barriers; epilogue compresses equal-row runs among each
// lane's 4 consecutive sorted tasks in registers, then fire-and-forget atomics.
__global__ __launch_bounds__(256, 3)
void spiral_mfma6_kernel(const unsigned short* __restrict__ x16,
                         const unsigned short* __restrict__ wp,
                         const float* __restrict__ bias,
                         const unsigned short* __restrict__ tidx,
                         const int* __restrict__ rows_s,
                         const float* __restrict__ vals_s,
                         float* __restrict__ out)
{
    const int bid  = blockIdx.x;
    const int b    = bid & 7;          // XCD swizzle: batch <-> XCD (x16/out L2-local)
    const int tile = bid >> 3;
    const int tid  = threadIdx.x;
    const int w    = tid >> 6;
    const int lane = tid & 63;
    const int quad = lane >> 4;
    const int m16  = lane & 15;
    const int z0w  = tile * TILE_T + 32 * w;   // wave's first sorted-task index

    // per-lane task metadata: lane L carries task z0w + (L&31) (coalesced)
    const int   zc   = min(z0w + (lane & 31), NNZ - 1);
    const int   rowv = rows_s[zc];
    const float valv = vals_s[zc];
    const uint4 p0 = *(const uint4*)(tidx + (size_t)zc * 16);
    const unsigned int p1 = *(const unsigned int*)(tidx + (size_t)zc * 16 + 8);
    int idx[9];
    idx[0] = p0.x & 0xffff;  idx[1] = p0.x >> 16;
    idx[2] = p0.y & 0xffff;  idx[3] = p0.y >> 16;
    idx[4] = p0.z & 0xffff;  idx[5] = p0.z >> 16;
    idx[6] = p0.w & 0xffff;  idx[7] = p0.w >> 16;
    idx[8] = p1 & 0xffff;

    const unsigned short* xb = x16 + (size_t)b * NVERT * CIN;

    // ---- all A-fragment gathers up front: one latency round-trip
    short8 A[2][9];
    #pragma unroll
    for (int s = 0; s < 9; ++s) {
        #pragma unroll
        for (int mt = 0; mt < 2; ++mt) {
            int tix = __shfl(idx[s], mt * 16 + m16);
            A[mt][s] = *(const short8*)(xb + (size_t)tix * CIN + quad * 8);
        }
    }

    floatx4 acc[2][4];
    #pragma unroll
    for (int mt = 0; mt < 2; ++mt)
        #pragma unroll
        for (int g = 0; g < 4; ++g) acc[mt][g] = (floatx4){0.f, 0.f, 0.f, 0.f};

    #pragma unroll
    for (int s = 0; s < 9; ++s) {
        short8 bf[4];
        #pragma unroll
        for (int g = 0; g < 4; ++g)
            bf[g] = *(const short8*)(wp + (size_t)((s * 4 + g) * 64 + lane) * 8);
        #pragma unroll
        for (int mt = 0; mt < 2; ++mt)
            #pragma unroll
            for (int g = 0; g < 4; ++g)
                acc[mt][g] = __builtin_amdgcn_mfma_f32_16x16x32_bf16(A[mt][s], bf[g], acc[mt][g], 0, 0, 0);
    }

    // ---- epilogue: register run-compression over 4 consecutive sorted tasks
    float bs[4];
    #pragma unroll
    for (int g = 0; g < 4; ++g) bs[g] = bias[g * 16 + m16];
    float* outb = out + (size_t)b * MVERT * COUT;

    #pragma unroll
    for (int mt = 0; mt < 2; ++mt) {
        int   rr[4]; float vv[4]; bool val[4];
        #pragma unroll
        for (int r = 0; r < 4; ++r) {
            const int tsk = mt * 16 + quad * 4 + r;        // C row = quad*4 + reg
            rr[r]  = __shfl(rowv, tsk);
            vv[r]  = __shfl(valv, tsk);
            val[r] = (z0w + tsk) < NNZ;
        }
        bool emit[4];   // last element of an equal-row run
        #pragma unroll
        for (int r = 0; r < 4; ++r)
            emit[r] = (r == 3) || (!val[r + 1 > 3 ? 3 : r + 1]) || (rr[r + 1 > 3 ? 3 : r + 1] != rr[r]);
        #pragma unroll
        for (int g = 0; g < 4; ++g) {
            const int ch = g * 16 + m16;
            float s = 0.0f;
            #pragma unroll
            for (int r = 0; r < 4; ++r) {
                if (val[r]) {
                    float y = acc[mt][g][r] + bs[g];
                    y = (y > 0.0f) ? y : (__expf(y) - 1.0f);
                    s += y * vv[r];
                    if (emit[r]) {
                        atomicAdd(outb + (size_t)rr[r] * COUT + ch, s);
                        s = 0.0f;
                    }
                }
            }
        }
    }
}

extern "C" void kernel_launch(void* const* d_in, const int* in_sizes, int n_in,
                              void* d_out, int out_size, void* d_ws, size_t ws_size,
                              hipStream_t stream) {
    const float* x      = (const float*)d_in[0];
    const float* w      = (const float*)d_in[1];
    const float* bias   = (const float*)d_in[2];
    const float* vals   = (const float*)d_in[3];
    const int*   spiral = (const int*)d_in[4];
    const int*   rows   = (const int*)d_in[5];
    const int*   cols   = (const int*)d_in[6];
    float* out = (float*)d_out;

    // ws layout
    char* base = (char*)d_ws;
    unsigned short* wp     = (unsigned short*)(base);                    //    36,864 B
    unsigned short* x16    = (unsigned short*)(base + 36864);            // 25,600,000 B
    int*            hist   = (int*)(base + 25636864);
    int*            off2   = (int*)(base + 25686864);
    int*            rows_s = (int*)(base + 25736864);
    float*          vals_s = (float*)(base + 26036896);
    unsigned short* tidx   = (unsigned short*)(base + 26186912);         //  1,200,000 B

    const int prep_grid = PRE_BLOCKS + PACK_BLOCKS + ZERO_BLOCKS + HZ_BLOCKS;
    prep_kernel<<<prep_grid, 256, 0, stream>>>(x, w, x16, wp, out, hist);
    hist_kernel<<<147, 256, 0, stream>>>(rows, hist);
    scan_kernel<<<1, 1024, 0, stream>>>(hist, off2);
    scatter_kernel<<<147, 256, 0, stream>>>(rows, cols, vals, spiral, off2,
                                            rows_s, vals_s, tidx);
    spiral_mfma6_kernel<<<BATCH * TPB, 256, 0, stream>>>(x16, wp, bias, tidx,
                                                         rows_s, vals_s, out);
}